// Round 5
// baseline (757.968 us; speedup 1.0000x reference)
//
#include <hip/hip_runtime.h>

typedef unsigned long long u64;
typedef unsigned int u32;
typedef float v2f __attribute__((ext_vector_type(2)));

// Problem constants (from reference setup_inputs / NUM_GROUP / GROUP_SIZE)
#define BATCH 32
#define NPTS  8192
#define NGRP  512
#define KNN_K 32

#define FPS_T 256                  // threads per FPS block (4 waves)
#define FPS_W (FPS_T / 64)         // 4 waves
#define PPAIR (NPTS / FPS_T / 2)   // 16 point-PAIRS per thread
#define KNN_WPB 4                  // waves (centers) per kNN block

// Exact IEEE (no FMA contraction) squared distance: ((dx*dx + dy*dy) + dz*dz)
__device__ __forceinline__ float sq3(float dx, float dy, float dz) {
    return __fadd_rn(__fadd_rn(__fmul_rn(dx, dx), __fmul_rn(dy, dy)), __fmul_rn(dz, dz));
}

// d >= 0 always (sum of squares) -> IEEE bits are order-monotonic.
// key = (d_bits << 32) | idx  ==> u64 ascending == (d, idx) lexicographic.
__device__ __forceinline__ u64 packdi(float d, int n) {
    return ((u64)__float_as_uint(d) << 32) | (u32)n;
}

__device__ __forceinline__ u64 umin64(u64 a, u64 b) { return a < b ? a : b; }
__device__ __forceinline__ u64 umax64(u64 a, u64 b) { return a > b ? a : b; }

__device__ __forceinline__ u64 shfl_xor_u64(u64 v, int m) {
    int lo = __shfl_xor((int)(u32)v, m, 64);
    int hi = __shfl_xor((int)(u32)(v >> 32), m, 64);
    return ((u64)(u32)hi << 32) | (u32)lo;
}

__device__ __forceinline__ u64 shfl_u64(u64 v, int src) {
    int lo = __shfl((int)(u32)v, src, 64);
    int hi = __shfl((int)(u32)(v >> 32), src, 64);
    return ((u64)(u32)hi << 32) | (u32)lo;
}

// ---- DPP wave-64 u64-max reduction (result valid in lane 63) --------------
// update_dpp(old=0, bound_ctrl=1): lanes with invalid DPP source read 0.
// 0 is a safe identity: every real key has low32 = ~n >= 0xFFFFE000 > 0.
template <int CTRL>
__device__ __forceinline__ u64 dpp_max_step(u64 k) {
    u32 plo = (u32)__builtin_amdgcn_update_dpp(0, (int)(u32)k, CTRL, 0xF, 0xF, true);
    u32 phi = (u32)__builtin_amdgcn_update_dpp(0, (int)(u32)(k >> 32), CTRL, 0xF, 0xF, true);
    u64 p = ((u64)phi << 32) | plo;
    return k > p ? k : p;
}
__device__ __forceinline__ u64 dpp_wave_max(u64 k) {
    k = dpp_max_step<0x111>(k);  // row_shr:1
    k = dpp_max_step<0x112>(k);  // row_shr:2
    k = dpp_max_step<0x114>(k);  // row_shr:4
    k = dpp_max_step<0x118>(k);  // row_shr:8   -> lanes 15/31/47/63 = row max
    k = dpp_max_step<0x142>(k);  // row_bcast15 -> lane31 = rows0-1, lane63 = rows2-3
    k = dpp_max_step<0x143>(k);  // row_bcast31 -> lane63 = full wave
    return k;
}

// Cross-lane bitonic sort: one u64 per lane -> ascending by lane index.
__device__ __forceinline__ u64 lane_sort64(u64 v, int lane) {
#pragma unroll
    for (int k = 2; k <= 64; k <<= 1) {
#pragma unroll
        for (int j = k >> 1; j > 0; j >>= 1) {
            u64 p = shfl_xor_u64(v, j);
            bool keepmin = (((lane & k) == 0) == ((lane & j) == 0));
            u64 mn = umin64(v, p), mx = umax64(v, p);
            v = keepmin ? mn : mx;
        }
    }
    return v;
}

// m, c both ascending-sorted across lanes; returns the lowest 64 of the 128,
// ascending-sorted. (reverse c, elementwise min -> bitonic, 6-level clean)
__device__ __forceinline__ u64 lane_merge64(u64 m, u64 c, int lane) {
    u64 cr = shfl_xor_u64(c, 63);
    u64 z = umin64(m, cr);
#pragma unroll
    for (int dd = 32; dd > 0; dd >>= 1) {
        u64 p = shfl_xor_u64(z, dd);
        u64 mn = umin64(z, p), mx = umax64(z, p);
        z = (lane & dd) ? mx : mn;
    }
    return z;
}

// ---------------------------------------------------------------------------
// FPS: one block per batch, 256 threads, 32 points/thread as 16 float2 pairs
// (v_pk_* packed fp32; contract(off) keeps per-op IEEE rounding == numpy).
// NO __syncthreads in the round loop: cross-wave exchange via a zero-init
// LDS table s_key[round][wave] + volatile spin (a real key is never 0, low
// word = ~n >= 0xFFFFE000). A wave can't pass round r until all 4 partials
// for r are published -> implicit sync without exec/vmcnt drain. Center
// coords buffered in LDS and written to global once, coalesced, at the end.
// ---------------------------------------------------------------------------
__global__ __launch_bounds__(FPS_T) void fps_kernel(const float* __restrict__ in,
                                                    float* __restrict__ centers) {
#pragma clang fp contract(off)
    __shared__ float sx[NPTS];
    __shared__ float sy[NPTS];
    __shared__ float sz[NPTS];
    __shared__ volatile u64 s_key[NGRP][FPS_W];  // 16 KB, 0 = "not yet"
    __shared__ float s_out[NGRP * 3];            // 6 KB center-coord buffer

    const int b = blockIdx.x;
    const int t = threadIdx.x;
    const int w = t >> 6;
    const float* xp = in + (size_t)b * 3 * NPTS;
    const float* yp = xp + NPTS;
    const float* zp = xp + 2 * NPTS;

    v2f xr[PPAIR], yr[PPAIR], zr[PPAIR], md[PPAIR];
#pragma unroll
    for (int i = 0; i < PPAIR; ++i) {
        int n = i * (2 * FPS_T) + 2 * t;       // pair covers points n, n+1
        xr[i] = *(const v2f*)(xp + n);
        yr[i] = *(const v2f*)(yp + n);
        zr[i] = *(const v2f*)(zp + n);
        *(v2f*)(sx + n) = xr[i];
        *(v2f*)(sy + n) = yr[i];
        *(v2f*)(sz + n) = zr[i];
        md[i] = (v2f){1e10f, 1e10f};
    }
#pragma unroll
    for (int i = t; i < NGRP * FPS_W; i += FPS_T) s_key[i / FPS_W][i % FPS_W] = 0;
    __syncthreads();  // the only barrier

    int cur = 0;
    for (int r = 0; r < NGRP; ++r) {
        const float cx = sx[cur], cy = sy[cur], cz = sz[cur];  // broadcast reads
        if (t == 0) {  // idxs[r] is the PRE-update farthest -> buffer its coords
            s_out[r * 3 + 0] = cx;
            s_out[r * 3 + 1] = cy;
            s_out[r * 3 + 2] = cz;
        }

        float bd0 = -1.0f, bd1 = -1.0f;
        int   bi0 = 0,     bi1 = 0;
#pragma unroll
        for (int i = 0; i < PPAIR; ++i) {
            v2f dx = xr[i] - cx;
            v2f dy = yr[i] - cy;
            v2f dz = zr[i] - cz;
            v2f dd = dx * dx + dy * dy + dz * dz;  // contract(off): 3 mul + 2 add
            md[i] = __builtin_elementwise_min(md[i], dd);
            int n = i * (2 * FPS_T) + 2 * t;
            if (md[i].x > bd0) { bd0 = md[i].x; bi0 = n; }      // strict >: first max
            if (md[i].y > bd1) { bd1 = md[i].y; bi1 = n + 1; }
        }
        // max (d, tie -> lowest n) == u64 max of (d_bits, ~n)
        u64 k0 = ((u64)__float_as_uint(bd0) << 32) | (u32)(~(u32)bi0);
        u64 k1 = ((u64)__float_as_uint(bd1) << 32) | (u32)(~(u32)bi1);
        u64 k = dpp_wave_max(umax64(k0, k1));
        if ((t & 63) == 63) s_key[r][w] = k;  // publish wave partial (lane 63)

        // spin until all 4 partials for round r are visible (broadcast reads)
        u64 p0, p1, p2, p3;
        do {
            p0 = s_key[r][0]; p1 = s_key[r][1];
            p2 = s_key[r][2]; p3 = s_key[r][3];
        } while ((p0 == 0) | (p1 == 0) | (p2 == 0) | (p3 == 0));
        u64 m = umax64(umax64(p0, p1), umax64(p2, p3));
        cur = (int)(~(u32)m);  // recover winning index
    }

    // coalesced final write of all centers
    float* cdst = centers + (size_t)b * NGRP * 3;
    for (int i = t; i < NGRP * 3; i += FPS_T) cdst[i] = s_out[i];
}

// ---------------------------------------------------------------------------
// kNN + gather: one wave per center. Wave-cooperative exact top-32 (see R2/R3
// notes): sorted-64 register list across lanes, tau = exact running 32nd,
// 1-deep per-lane pending queue, ballot-triggered sort+merge flush.
// ---------------------------------------------------------------------------
__global__ __launch_bounds__(KNN_WPB * 64) void knn_kernel(const float* __restrict__ in,
                                                           const float* __restrict__ centers,
                                                           float* __restrict__ out) {
    const int wave = threadIdx.x >> 6;
    const int lane = threadIdx.x & 63;
    const int cid  = blockIdx.x * KNN_WPB + wave;   // [0, B*G)
    const int b    = cid >> 9;                      // /NGRP

    const float* xp = in + (size_t)b * 3 * NPTS;
    const float* yp = xp + NPTS;
    const float* zp = xp + 2 * NPTS;

    const float cx = centers[cid * 3 + 0];
    const float cy = centers[cid * 3 + 1];
    const float cz = centers[cid * 3 + 2];

    // seed: column 0 (points 0..63), exact sorted top-64
    float x = xp[lane], y = yp[lane], z = zp[lane];
    u64 m = packdi(sq3(__fsub_rn(x, cx), __fsub_rn(y, cy), __fsub_rn(z, cz)), lane);
    m = lane_sort64(m, lane);
    u64 tau = shfl_u64(m, 31);
    u64 q = ~0ull;  // empty pending slot

    float nx = xp[64 + lane], ny = yp[64 + lane], nz = zp[64 + lane];
#pragma unroll 1
    for (int j = 1; j < NPTS / 64; ++j) {
        x = nx; y = ny; z = nz;
        if (j + 1 < NPTS / 64) {  // 1-deep prefetch
            int n2 = (j + 1) * 64 + lane;
            nx = xp[n2]; ny = yp[n2]; nz = zp[n2];
        }
        float d = sq3(__fsub_rn(x, cx), __fsub_rn(y, cy), __fsub_rn(z, cz));
        u64 kk = packdi(d, j * 64 + lane);
        bool cand = kk < tau;  // strict: kk == tau is already in m
        if (__ballot(cand && (q != ~0ull))) {  // someone needs a free slot
            u64 c = lane_sort64(q, lane);
            m = lane_merge64(m, c, lane);
            tau = shfl_u64(m, 31);   // tau only decreases; stale cand harmless
            q = ~0ull;
        }
        if (cand) q = kk;
    }
    if (__ballot(q != ~0ull)) {  // drain
        u64 c = lane_sort64(q, lane);
        m = lane_merge64(m, c, lane);
    }

    if (lane < KNN_K) {
        int n = (int)(u32)m;
        size_t o = (size_t)cid * (KNN_K * 3) + (size_t)lane * 3;
        out[o + 0] = __fsub_rn(xp[n], cx);
        out[o + 1] = __fsub_rn(yp[n], cy);
        out[o + 2] = __fsub_rn(zp[n], cz);
    }
}

extern "C" void kernel_launch(void* const* d_in, const int* in_sizes, int n_in,
                              void* d_out, int out_size, void* d_ws, size_t ws_size,
                              hipStream_t stream) {
    const float* in  = (const float*)d_in[0];
    float* out       = (float*)d_out;
    float* centers   = out + (size_t)BATCH * NGRP * KNN_K * 3;  // second output section

    fps_kernel<<<BATCH, FPS_T, 0, stream>>>(in, centers);
    knn_kernel<<<(BATCH * NGRP) / KNN_WPB, KNN_WPB * 64, 0, stream>>>(in, centers, out);
}

// Round 6
// 631.698 us; speedup vs baseline: 1.1999x; 1.1999x over previous
//
#include <hip/hip_runtime.h>

typedef unsigned long long u64;
typedef unsigned int u32;
typedef float v2f __attribute__((ext_vector_type(2)));
typedef float v4f __attribute__((ext_vector_type(4)));

// Problem constants (from reference setup_inputs / NUM_GROUP / GROUP_SIZE)
#define BATCH 32
#define NPTS  8192
#define NGRP  512
#define KNN_K 32

#define FPS_T 256                  // threads per FPS block (4 waves)
#define FPS_W (FPS_T / 64)         // 4 waves
#define PPAIR (NPTS / FPS_T / 2)   // 16 point-PAIRS per thread
#define KNN_WPB 4                  // waves (centers) per kNN block
#define QCAP 128                   // per-wave LDS candidate buffer depth

// Exact IEEE (no FMA contraction) squared distance: ((dx*dx + dy*dy) + dz*dz)
__device__ __forceinline__ float sq3(float dx, float dy, float dz) {
    return __fadd_rn(__fadd_rn(__fmul_rn(dx, dx), __fmul_rn(dy, dy)), __fmul_rn(dz, dz));
}

// d >= 0 always (sum of squares) -> IEEE bits are order-monotonic.
// key = (d_bits << 32) | idx  ==> u64 ascending == (d, idx) lexicographic.
__device__ __forceinline__ u64 packdi(float d, int n) {
    return ((u64)__float_as_uint(d) << 32) | (u32)n;
}

__device__ __forceinline__ u64 umin64(u64 a, u64 b) { return a < b ? a : b; }
__device__ __forceinline__ u64 umax64(u64 a, u64 b) { return a > b ? a : b; }

__device__ __forceinline__ u64 shfl_xor_u64(u64 v, int m) {
    int lo = __shfl_xor((int)(u32)v, m, 64);
    int hi = __shfl_xor((int)(u32)(v >> 32), m, 64);
    return ((u64)(u32)hi << 32) | (u32)lo;
}

__device__ __forceinline__ u64 shfl_u64(u64 v, int src) {
    int lo = __shfl((int)(u32)v, src, 64);
    int hi = __shfl((int)(u32)(v >> 32), src, 64);
    return ((u64)(u32)hi << 32) | (u32)lo;
}

// ---- DPP wave-64 u64-max reduction (result valid in lane 63) --------------
// update_dpp(old=0, bound_ctrl=1): lanes with invalid DPP source read 0.
// 0 is a safe identity: every real key has low32 = ~n >= 0xFFFFE000 > 0.
template <int CTRL>
__device__ __forceinline__ u64 dpp_max_step(u64 k) {
    u32 plo = (u32)__builtin_amdgcn_update_dpp(0, (int)(u32)k, CTRL, 0xF, 0xF, true);
    u32 phi = (u32)__builtin_amdgcn_update_dpp(0, (int)(u32)(k >> 32), CTRL, 0xF, 0xF, true);
    u64 p = ((u64)phi << 32) | plo;
    return k > p ? k : p;
}
__device__ __forceinline__ u64 dpp_wave_max(u64 k) {
    k = dpp_max_step<0x111>(k);  // row_shr:1
    k = dpp_max_step<0x112>(k);  // row_shr:2
    k = dpp_max_step<0x114>(k);  // row_shr:4
    k = dpp_max_step<0x118>(k);  // row_shr:8   -> lanes 15/31/47/63 = row max
    k = dpp_max_step<0x142>(k);  // row_bcast15 -> lane31 = rows0-1, lane63 = rows2-3
    k = dpp_max_step<0x143>(k);  // row_bcast31 -> lane63 = full wave
    return k;
}

// Cross-lane bitonic sort: one u64 per lane -> ascending by lane index.
__device__ __forceinline__ u64 lane_sort64(u64 v, int lane) {
#pragma unroll
    for (int k = 2; k <= 64; k <<= 1) {
#pragma unroll
        for (int j = k >> 1; j > 0; j >>= 1) {
            u64 p = shfl_xor_u64(v, j);
            bool keepmin = (((lane & k) == 0) == ((lane & j) == 0));
            u64 mn = umin64(v, p), mx = umax64(v, p);
            v = keepmin ? mn : mx;
        }
    }
    return v;
}

// m, c both ascending-sorted across lanes; returns the lowest 64 of the 128,
// ascending-sorted. (reverse c, elementwise min -> bitonic, 6-level clean)
__device__ __forceinline__ u64 lane_merge64(u64 m, u64 c, int lane) {
    u64 cr = shfl_xor_u64(c, 63);
    u64 z = umin64(m, cr);
#pragma unroll
    for (int dd = 32; dd > 0; dd >>= 1) {
        u64 p = shfl_xor_u64(z, dd);
        u64 mn = umin64(z, p), mx = umax64(z, p);
        z = (lane & dd) ? mx : mn;
    }
    return z;
}

// ---------------------------------------------------------------------------
// FPS: one block per batch, 256 threads, 32 points/thread as 16 float2 pairs
// (contract(off) keeps per-op IEEE rounding == numpy). Round loop: dist+min
// ONLY (no in-loop argmax tracking); post-loop max-tree + descending
// equality scan recovers the lowest matching index (identical semantics to
// strict-> ascending tracking, fewer ops, no serial chain). Winner coords
// fetched with a single ds_read_b128 from padded s_pts. Centers buffered in
// LDS, written coalesced once at the end. One __syncthreads per round.
// ---------------------------------------------------------------------------
__global__ __launch_bounds__(FPS_T) void fps_kernel(const float* __restrict__ in,
                                                    float* __restrict__ centers) {
#pragma clang fp contract(off)
    __shared__ v4f s_pts[NPTS];          // 128 KB padded points
    __shared__ u64 s_key[2][FPS_W];      // double-buffered wave partials
    __shared__ float s_out[NGRP * 3];    // 6 KB center-coord buffer

    const int b = blockIdx.x;
    const int t = threadIdx.x;
    const int w = t >> 6;
    const float* xp = in + (size_t)b * 3 * NPTS;
    const float* yp = xp + NPTS;
    const float* zp = xp + 2 * NPTS;

    v2f xr[PPAIR], yr[PPAIR], zr[PPAIR], md[PPAIR];
#pragma unroll
    for (int i = 0; i < PPAIR; ++i) {
        int n = i * (2 * FPS_T) + 2 * t;       // pair covers points n, n+1
        xr[i] = *(const v2f*)(xp + n);
        yr[i] = *(const v2f*)(yp + n);
        zr[i] = *(const v2f*)(zp + n);
        s_pts[n]     = (v4f){xr[i].x, yr[i].x, zr[i].x, 0.0f};
        s_pts[n + 1] = (v4f){xr[i].y, yr[i].y, zr[i].y, 0.0f};
        md[i] = (v2f){1e10f, 1e10f};
    }
    __syncthreads();

    int cur = 0;
    for (int r = 0; r < NGRP; ++r) {
        const v4f cc = s_pts[cur];             // one ds_read_b128 (broadcast)
        const float cx = cc.x, cy = cc.y, cz = cc.z;
        if (t == 0) {  // idxs[r] is the PRE-update farthest -> buffer coords
            s_out[r * 3 + 0] = cx;
            s_out[r * 3 + 1] = cy;
            s_out[r * 3 + 2] = cz;
        }

        // dist + min only (no tracking): best ILP, fewest ops
#pragma unroll
        for (int i = 0; i < PPAIR; ++i) {
            v2f dx = xr[i] - cx;
            v2f dy = yr[i] - cy;
            v2f dz = zr[i] - cz;
            v2f dd = dx * dx + dy * dy + dz * dz;  // contract(off): 3 mul + 2 add
            md[i] = __builtin_elementwise_min(md[i], dd);
        }
        // max-tree over the 32 md values (v_max returns operand bits exactly)
        v2f mx = md[0];
#pragma unroll
        for (int i = 1; i < PPAIR; ++i) mx = __builtin_elementwise_max(mx, md[i]);
        float mxs = fmaxf(mx.x, mx.y);
        // descending equality scan -> lowest n with md == mxs
        int c = 0;
#pragma unroll
        for (int i = PPAIR - 1; i >= 0; --i) {
            int n = i * (2 * FPS_T) + 2 * t;
            if (md[i].y == mxs) c = n + 1;
            if (md[i].x == mxs) c = n;
        }
        // max (d, tie -> lowest n) == u64 max of (d_bits, ~n)
        u64 k = ((u64)__float_as_uint(mxs) << 32) | (u32)(~(u32)c);
        k = dpp_wave_max(k);
        if ((t & 63) == 63) s_key[r & 1][w] = k;  // lane 63 holds wave winner
        __syncthreads();
        u64 m = umax64(umax64(s_key[r & 1][0], s_key[r & 1][1]),
                       umax64(s_key[r & 1][2], s_key[r & 1][3]));
        cur = (int)(~(u32)m);  // recover winning index
    }

    __syncthreads();  // t0's last s_out writes
    float* cdst = centers + (size_t)b * NGRP * 3;
    for (int i = t; i < NGRP * 3; i += FPS_T) cdst[i] = s_out[i];
}

// ---------------------------------------------------------------------------
// kNN + gather: one wave per center. Wave-cooperative exact top-32 with a
// DEFERRED LDS candidate buffer: m = sorted-64 register list (lanes 0..31 =
// exact running top-32 of all merged keys), tau = m[31] (exact 32nd).
// Candidates (kk < tau) are compacted into a 128-deep per-wave LDS buffer
// via ballot+mbcnt (no atomics); sort64+merge fires only when >=64 have
// accumulated (~5-7 times total vs ~30 per-collision flushes). Strict <
// filter + unique keys => exactness; drain loop merges leftovers.
// ---------------------------------------------------------------------------
__global__ __launch_bounds__(KNN_WPB * 64) void knn_kernel(const float* __restrict__ in,
                                                           const float* __restrict__ centers,
                                                           float* __restrict__ out) {
    __shared__ u64 sbuf[KNN_WPB][QCAP];  // 4 KB candidate buffers

    const int wave = threadIdx.x >> 6;
    const int lane = threadIdx.x & 63;
    const int cid  = blockIdx.x * KNN_WPB + wave;   // [0, B*G)
    const int b    = cid >> 9;                      // /NGRP

    const float* xp = in + (size_t)b * 3 * NPTS;
    const float* yp = xp + NPTS;
    const float* zp = xp + 2 * NPTS;

    const float cx = centers[cid * 3 + 0];
    const float cy = centers[cid * 3 + 1];
    const float cz = centers[cid * 3 + 2];

    // seed: column 0 (points 0..63), exact sorted top-64
    float x = xp[lane], y = yp[lane], z = zp[lane];
    u64 m = packdi(sq3(__fsub_rn(x, cx), __fsub_rn(y, cy), __fsub_rn(z, cz)), lane);
    m = lane_sort64(m, lane);
    u64 tau = shfl_u64(m, 31);
    int cnt = 0;  // wave-uniform buffered-candidate count

    float nx = xp[64 + lane], ny = yp[64 + lane], nz = zp[64 + lane];
#pragma unroll 1
    for (int j = 1; j < NPTS / 64; ++j) {
        x = nx; y = ny; z = nz;
        if (j + 1 < NPTS / 64) {  // 1-deep prefetch
            int n2 = (j + 1) * 64 + lane;
            nx = xp[n2]; ny = yp[n2]; nz = zp[n2];
        }
        float d = sq3(__fsub_rn(x, cx), __fsub_rn(y, cy), __fsub_rn(z, cz));
        u64 kk = packdi(d, j * 64 + lane);
        bool cand = kk < tau;  // strict: excluded keys provably > global 32nd
        u64 mask = __ballot(cand);
        if (mask) {
            // compact append via mbcnt (lanes below me in mask)
            u32 below = __builtin_amdgcn_mbcnt_hi(
                (u32)(mask >> 32), __builtin_amdgcn_mbcnt_lo((u32)mask, 0));
            if (cand) sbuf[wave][cnt + below] = kk;
            cnt += (int)__popcll(mask);
            if (cnt >= 64) {  // flush a full batch of 64
                u64 c = sbuf[wave][lane];
                c = lane_sort64(c, lane);
                m = lane_merge64(m, c, lane);
                tau = shfl_u64(m, 31);
                int rem = cnt - 64;
                if (lane < rem) sbuf[wave][lane] = sbuf[wave][64 + lane];
                cnt = rem;
            }
        }
    }
    // drain leftovers (<= 127 keys -> at most 2 batches)
    while (cnt > 0) {
        int take = cnt < 64 ? cnt : 64;
        u64 v = sbuf[wave][lane];
        u64 c = (lane < take) ? v : ~0ull;
        c = lane_sort64(c, lane);
        m = lane_merge64(m, c, lane);
        int rem = cnt - take;
        if (lane < rem) sbuf[wave][lane] = sbuf[wave][64 + lane];
        cnt = rem;
    }

    // lanes 0..31 hold the exact global top-32, ascending (== stable top_k)
    if (lane < KNN_K) {
        int n = (int)(u32)m;
        size_t o = (size_t)cid * (KNN_K * 3) + (size_t)lane * 3;
        out[o + 0] = __fsub_rn(xp[n], cx);
        out[o + 1] = __fsub_rn(yp[n], cy);
        out[o + 2] = __fsub_rn(zp[n], cz);
    }
}

extern "C" void kernel_launch(void* const* d_in, const int* in_sizes, int n_in,
                              void* d_out, int out_size, void* d_ws, size_t ws_size,
                              hipStream_t stream) {
    const float* in  = (const float*)d_in[0];
    float* out       = (float*)d_out;
    float* centers   = out + (size_t)BATCH * NGRP * KNN_K * 3;  // second output section

    fps_kernel<<<BATCH, FPS_T, 0, stream>>>(in, centers);
    knn_kernel<<<(BATCH * NGRP) / KNN_WPB, KNN_WPB * 64, 0, stream>>>(in, centers, out);
}